// Round 1
// baseline (24709.511 us; speedup 1.0000x reference)
//
#include <hip/hip_runtime.h>

#define EMB 300
#define VU 50000
#define VQ 30000
#define NCOLS 64
#define COLLEN 6
#define NTURNS 6
#define INLEN 128
#define TSTEPS 63
#define VOUT 30064
#define MAXK 5
#define NWD 60

__device__ __forceinline__ float sigf(float x){ return 1.0f/(1.0f+__expf(-x)); }
__device__ __forceinline__ float tanhf_(float x){ return 1.0f - 2.0f/(1.0f+__expf(2.0f*x)); }
__device__ __forceinline__ float wsum(float v){
#pragma unroll
  for (int o=32;o;o>>=1) v += __shfl_xor(v,o);
  return v;
}
__device__ __forceinline__ float wmax(float v){
#pragma unroll
  for (int o=32;o;o>>=1) v = fmaxf(v,__shfl_xor(v,o));
  return v;
}

// global barrier across NWD co-resident workgroups (monotone counter, no reset)
__device__ __forceinline__ void gbar(int* bar, int target)
{
  __syncthreads();
  if (threadIdx.x == 0) {
    __hip_atomic_fetch_add(bar, 1, __ATOMIC_ACQ_REL, __HIP_MEMORY_SCOPE_AGENT);
    while (__hip_atomic_load(bar, __ATOMIC_ACQUIRE, __HIP_MEMORY_SCOPE_AGENT) < target)
      __builtin_amdgcn_s_sleep(2);
  }
  __syncthreads();
}

// ---------------- generic transpose: out[c][r] = in[r][c] ----------------
__global__ void k_transpose(const float* __restrict__ in, float* __restrict__ out, int R, int C)
{
  __shared__ float tile[32][33];
  const int rb = blockIdx.y*32, cb = blockIdx.x*32;
  const int tx = threadIdx.x & 31, ty = threadIdx.x >> 5;
  for (int k = 0; k < 32; k += 8) {
    int r = rb + ty + k, c = cb + tx;
    if (r < R && c < C) tile[ty+k][tx] = in[(size_t)r*C + c];
  }
  __syncthreads();
  for (int k = 0; k < 32; k += 8) {
    int c = cb + ty + k, r = rb + tx;
    if (c < C && r < R) out[(size_t)c*R + r] = tile[tx][ty+k];
  }
}

// ---------------- schema column BiLSTM (layer 0), one WG per (col,dir) ----------------
__global__ void k_schema(const float* __restrict__ temb, const int* __restrict__ stok,
                         const float* __restrict__ Wih, const float* __restrict__ Whh,
                         const float* __restrict__ bb, float* __restrict__ SE0)
{
  const int col = blockIdx.x >> 1, dir = blockIdx.x & 1, tid = threadIdx.x;
  __shared__ float hl[150], cl[150], zl[600];
  if (tid < 150) { hl[tid]=0.f; cl[tid]=0.f; }
  __syncthreads();
  const float* Wi = Wih + (size_t)dir*600*300;
  const float* Wh = Whh + (size_t)dir*600*150;
  const float* bd = bb + dir*600;
  for (int s = 0; s < COLLEN; ++s) {
    const int pos = dir ? (COLLEN-1-s) : s;
    const int tok = stok[col*COLLEN + pos];
    const float* x = temb + (size_t)tok*300;
    for (int g = tid; g < 600; g += 256) {
      float a = bd[g];
      const float* wi = Wi + (size_t)g*300;
      for (int c = 0; c < 300; ++c) a += x[c]*wi[c];
      const float* wh = Wh + (size_t)g*150;
      for (int j = 0; j < 150; ++j) a += hl[j]*wh[j];
      zl[g] = a;
    }
    __syncthreads();
    if (tid < 150) {
      float ii=zl[tid], ff=zl[150+tid], gg=zl[300+tid], oo=zl[450+tid];
      float cn = sigf(ff)*cl[tid] + sigf(ii)*tanhf_(gg);
      cl[tid]=cn; hl[tid]=sigf(oo)*tanhf_(cn);
    }
    __syncthreads();
  }
  if (tid < 150) SE0[(size_t)col*300 + dir*150 + tid] = hl[tid];
}

// ---------------- input token embedding ----------------
__global__ void k_embed_in(const float* __restrict__ utter, const float* __restrict__ SEi,
                           const int* __restrict__ iseq, float* __restrict__ x)
{
  for (int i = blockIdx.x*256 + threadIdx.x; i < INLEN*300; i += gridDim.x*256) {
    int p = i/300, d = i - p*300;
    int t = iseq[p];
    x[i] = (t < VU) ? utter[(size_t)t*300 + d] : SEi[(size_t)(t-VU)*300 + d];
  }
}

// ---------------- Xg[pos][g] = x[pos]@Wih.T + b (per-layer, both dirs = 1200 gates) ----------------
__global__ void k_gemm_xg(const float* __restrict__ x, const float* __restrict__ WihL,
                          const float* __restrict__ bL, float* __restrict__ Xg)
{
  const int g = blockIdx.x*256 + threadIdx.x;
  if (g >= 1200) return;
  const int p0 = blockIdx.y*16;
  const float b = bL[g];
  const float* w = WihL + (size_t)g*300;
  float acc[16];
#pragma unroll
  for (int t = 0; t < 16; ++t) acc[t] = b;
  for (int c = 0; c < 300; ++c) {
    float wv = w[c];
#pragma unroll
    for (int t = 0; t < 16; ++t) acc[t] += wv * x[(size_t)(p0+t)*300 + c];  // uniform -> s_load
  }
#pragma unroll
  for (int t = 0; t < 16; ++t) Xg[(size_t)(p0+t)*1200 + g] = acc[t];
}

// ---------------- BiLSTM recurrence; grid=2 (fwd/bwd), Whh in VGPRs ----------------
__global__ __launch_bounds__(640) void k_rec(
    const float* __restrict__ Xg, const float* __restrict__ WhhTL,
    float* __restrict__ ys, float* __restrict__ fh, float* __restrict__ fc)
{
  const int dir = blockIdx.x, tid = threadIdx.x;
  __shared__ __align__(16) float hl[152];
  __shared__ float cl[152], zl[600];
  float w[150];
  const float* wt = WhhTL + (size_t)dir*150*600;
  if (tid < 600) {
#pragma unroll
    for (int j = 0; j < 150; ++j) w[j] = wt[(size_t)j*600 + tid];
  }
  if (tid < 152) { hl[tid] = 0.f; cl[tid] = 0.f; }
  __syncthreads();
  for (int s = 0; s < INLEN; ++s) {
    const int pos = dir ? (INLEN-1-s) : s;
    if (tid < 600) {
      float acc = Xg[(size_t)pos*1200 + dir*600 + tid];
      const float4* h4 = (const float4*)hl;
#pragma unroll
      for (int j4 = 0; j4 < 37; ++j4) {
        float4 h = h4[j4];
        acc += w[4*j4]*h.x + w[4*j4+1]*h.y + w[4*j4+2]*h.z + w[4*j4+3]*h.w;
      }
      acc += w[148]*hl[148] + w[149]*hl[149];
      zl[tid] = acc;
    }
    __syncthreads();
    if (tid < 150) {
      float ii=zl[tid], ff=zl[150+tid], gg=zl[300+tid], oo=zl[450+tid];
      float cn = sigf(ff)*cl[tid] + sigf(ii)*tanhf_(gg);
      cl[tid] = cn;
      float hn = sigf(oo)*tanhf_(cn);
      hl[tid] = hn;
      ys[(size_t)pos*300 + dir*150 + tid] = hn;
    }
    __syncthreads();
  }
  if (tid < 150) { fh[dir*150 + tid] = hl[tid]; fc[dir*150 + tid] = cl[tid]; }
}

// ---------------- schema update: SEo = SEi + softmax(SEi@ys2.T)@ys2 ----------------
__global__ void k_schema_upd(const float* __restrict__ SEi, const float* __restrict__ ys2,
                             float* __restrict__ SEo)
{
  const int row = blockIdx.x, tid = threadIdx.x;
  __shared__ float sl[300], al[128], red[4];
  for (int d = tid; d < 300; d += 256) sl[d] = SEi[(size_t)row*300 + d];
  __syncthreads();
  if (tid < 128) {
    float a = 0;
    const float* yr = ys2 + (size_t)tid*300;
    for (int d = 0; d < 300; ++d) a += sl[d]*yr[d];
    al[tid] = a;
  }
  __syncthreads();
  if (tid < 64) { float m = fmaxf(al[tid], al[tid+64]); m = wmax(m); if (tid==0) red[0]=m; }
  __syncthreads();
  if (tid < 128) al[tid] = __expf(al[tid] - red[0]);
  __syncthreads();
  if (tid < 64) { float s = al[tid] + al[tid+64]; s = wsum(s); if (tid==0) red[1]=s; }
  __syncthreads();
  const float invz = 1.0f/red[1];
  for (int d = tid; d < 300; d += 256) {
    float a = sl[d];
    for (int j = 0; j < 128; ++j) a += (al[j]*invz) * ys2[(size_t)j*300 + d];
    SEo[(size_t)row*300 + d] = a;
  }
}

// ---------------- h0/c0 history attention + history append + barrier reset ----------------
__global__ void k_h0c0(const float* __restrict__ fh, const float* __restrict__ fc,
                       float* __restrict__ HH, float* __restrict__ CH,
                       float* __restrict__ XH, const float* __restrict__ ys2,
                       const float* __restrict__ Wq, const float* __restrict__ Wk,
                       const float* __restrict__ av,
                       float* __restrict__ h0, float* __restrict__ c0,
                       int turn, int* __restrict__ bar)
{
  const int tid = threadIdx.x;
  if (blockIdx.x > 0) {
    if (turn < MAXK) {
      for (int i = (blockIdx.x-1)*256 + tid; i < INLEN*300; i += 60*256)
        XH[(size_t)turn*INLEN*300 + i] = ys2[i];
      if (blockIdx.x == 1)
        for (int d = tid; d < 300; d += 256) { HH[turn*300+d] = fh[d]; CH[turn*300+d] = fc[d]; }
    }
    return;
  }
  if (tid == 0) __hip_atomic_store(bar, 0, __ATOMIC_RELAXED, __HIP_MEMORY_SCOPE_AGENT);
  if (turn == 0) {
    for (int d = tid; d < 300; d += 256) { h0[d] = fh[d]; c0[d] = fc[d]; }
    return;
  }
  __shared__ float ql[300], qw[300], h0n[300], red[4], alsc[8];
  const int nh = turn;   // entries 0..turn-1 (turn <= 5)
  for (int d = tid; d < 300; d += 256) ql[d] = fh[d];
  __syncthreads();
  for (int rep = 0; rep < 2; ++rep) {
    const float* keys = rep ? CH : HH;
    for (int c = tid; c < 300; c += 256) {
      float a = 0;
      for (int d = 0; d < 300; ++d) a += ql[d]*Wq[(size_t)d*300 + c];
      qw[c] = a;
    }
    __syncthreads();
    for (int k = 0; k < nh; ++k) {
      const float* Kr = keys + (size_t)k*300;
      float part = 0;
      for (int c = tid; c < 300; c += 256) {
        float kw = 0;
        for (int d = 0; d < 300; ++d) kw += Kr[d]*Wk[(size_t)d*300 + c];
        part += av[c]*tanhf_(qw[c] + kw);
      }
      part = wsum(part);
      if ((tid & 63) == 0) red[tid >> 6] = part;
      __syncthreads();
      if (tid == 0) alsc[k] = red[0]+red[1]+red[2]+red[3];
      __syncthreads();
    }
    if (tid == 0) {
      float m = -1e30f;
      for (int k = 0; k < nh; ++k) m = fmaxf(m, alsc[k]);
      float z = 0;
      for (int k = 0; k < nh; ++k) { alsc[k] = __expf(alsc[k]-m); z += alsc[k]; }
      for (int k = 0; k < nh; ++k) alsc[k] /= z;
    }
    __syncthreads();
    if (rep == 0) {
      for (int c = tid; c < 300; c += 256) {
        float a = ql[c];                         // = fh[c]
        for (int k = 0; k < nh; ++k) a += alsc[k]*keys[(size_t)k*300 + c];
        h0n[c] = a; h0[c] = a;
      }
      __syncthreads();
      for (int d = tid; d < 300; d += 256) ql[d] = fc[d];
      __syncthreads();
    } else {
      for (int c = tid; c < 300; c += 256) {
        float a = h0n[c];
        for (int k = 0; k < nh; ++k) a += alsc[k]*keys[(size_t)k*300 + c];
        c0[c] = a;
      }
    }
  }
}

// ---------------- per-turn key tables ----------------
__device__ __forceinline__ const float* key_ptr(int j, int nin, const float* SE1,
                                                const float* XH, const float* OH, int* fam)
{
  if (j < 64) { *fam = 0; return SE1 + (size_t)j*300; }
  if (j < 64+nin) { *fam = 1; return XH + (size_t)(j-64)*300; }
  *fam = 2; return OH + (size_t)(j-64-nin)*300;
}

__global__ void k_kw(const float* __restrict__ SE1, const float* __restrict__ XH,
                     const float* __restrict__ OH, const float* __restrict__ Wk,
                     float* __restrict__ KW, int nin, int nout)
{
  int fam;
  const int j = blockIdx.x;
  const float* Kr = key_ptr(j, nin, SE1, XH, OH, &fam);
  const float* W = Wk + (size_t)(1+fam)*90000;
  for (int c = threadIdx.x; c < 300; c += 256) {
    float a = 0;
    for (int d = 0; d < 300; ++d) a += Kr[d]*W[(size_t)d*300 + c];
    KW[(size_t)j*300 + c] = a;
  }
}

__global__ void k_g1k(const float* __restrict__ SE1, const float* __restrict__ XH,
                      const float* __restrict__ OH, const float* __restrict__ Wih0,
                      float* __restrict__ G1K, int nin, int nout)
{
  int fam;
  const int j = blockIdx.x;
  const float* Kr = key_ptr(j, nin, SE1, XH, OH, &fam);
  const int cb = 300 + fam*300;
  for (int r = threadIdx.x; r < 1200; r += 256) {
    float a = 0;
    const float* w = Wih0 + (size_t)r*1200 + cb;
    for (int c = 0; c < 300; ++c) a += Kr[c]*w[c];
    G1K[(size_t)j*1200 + r] = a;
  }
}

__global__ void k_g2k(const float* __restrict__ SE1, const float* __restrict__ XH,
                      const float* __restrict__ OH, const float* __restrict__ tW,
                      float* __restrict__ G2K, int nin, int nout)
{
  int fam;
  const int j = blockIdx.x;
  const float* Kr = key_ptr(j, nin, SE1, XH, OH, &fam);
  const int cb = 300 + fam*300;
  for (int r = threadIdx.x; r < 300; r += 256) {
    float a = 0;
    const float* w = tW + (size_t)r*1200 + cb;
    for (int c = 0; c < 300; ++c) a += Kr[c]*w[c];
    G2K[(size_t)j*300 + r] = a;
  }
}

// ---------------- Ew[t] = embed(gt[t])@Wih0[:, :300].T + b0 ----------------
__global__ void k_ew(const int* __restrict__ gt, const float* __restrict__ qemb,
                     const float* __restrict__ SE1, const float* __restrict__ Wih0,
                     const float* __restrict__ b0, float* __restrict__ Ew)
{
  const int t = blockIdx.x;
  const int tok = gt[t];
  const float* e = (tok < VQ) ? qemb + (size_t)tok*300 : SE1 + (size_t)(tok-VQ)*300;
  for (int r = threadIdx.x; r < 1200; r += 256) {
    float a = b0[r];
    const float* w = Wih0 + (size_t)r*1200;
    for (int c = 0; c < 300; ++c) a += e[c]*w[c];
    Ew[(size_t)t*1200 + r] = a;
  }
}

// ---------------- persistent decoder recurrence: 60 WGs, 4 global barriers/step ----------------
__global__ __launch_bounds__(256) void k_dec(
    const float* __restrict__ KW, const float* __restrict__ G1KT,
    const float* __restrict__ Ew, const float* __restrict__ WqT,
    const float* __restrict__ av,
    const float* __restrict__ Whh0, const float* __restrict__ Wih1,
    const float* __restrict__ Whh1, const float* __restrict__ b1,
    const float* __restrict__ h0, const float* __restrict__ c0,
    float* __restrict__ h1b, float* __restrict__ h2b,
    float* __restrict__ qWb, float* __restrict__ scb,
    float* __restrict__ Alog, float* __restrict__ H2log,
    int nin, int nout, int* __restrict__ bar)
{
  const int NK = 64 + nin + nout;
  const int w = blockIdx.x, tid = threadIdx.x;
  const int wv = tid >> 6, ln = tid & 63;
  __shared__ float dhl[300], h1l[300], qWl[900], scl[1024], vl[900];
  __shared__ float pre1[20], pre2[20], zl[20], c1l[5], c2l[5];
  __shared__ float rm[3], rz[3], wr0[4], wr1[4], wr2[4];
  int phase = 0;
  for (int i = tid; i < 900; i += 256) vl[i] = av[300 + i];

  for (int t = 0; t < TSTEPS; ++t) {
    const float* dhs = t ? h2b : h0;
    const float* h1s = t ? h1b : h0;
    __syncthreads();
    for (int i = tid; i < 300; i += 256) { dhl[i] = dhs[i]; h1l[i] = h1s[i]; }
    __syncthreads();
    // ---- PA: qW slice + Whh0/Whh1 pre-gates ----
    for (int r = 0; r < 4; ++r) {
      int o = r*4 + wv;
      if (o < 15) {
        int q = w*15 + o, fam = q/300, c = q - fam*300;
        const float* rw = WqT + ((size_t)(1+fam)*300 + c)*300;
        float a = 0;
        for (int d = ln; d < 300; d += 64) a += dhl[d]*rw[d];
        a = wsum(a);
        if (ln==0) qWb[q] = a;
      }
    }
    for (int r = 0; r < 5; ++r) {
      int o = r*4 + wv;
      int k = o >> 2, m = o & 3;
      int row = w*5 + k + 300*m;
      float a1 = 0, a2 = 0;
      const float* w1 = Whh0 + (size_t)row*300;
      const float* w2 = Whh1 + (size_t)row*300;
      for (int d = ln; d < 300; d += 64) { a1 += h1l[d]*w1[d]; a2 += dhl[d]*w2[d]; }
      a1 = wsum(a1); a2 = wsum(a2);
      if (ln==0) { pre1[o] = a1; pre2[o] = a2 + b1[row]; }
    }
    gbar(bar, (++phase)*NWD);
    // ---- PB: attention scores ----
    for (int i = tid; i < 900; i += 256) qWl[i] = qWb[i];
    __syncthreads();
    for (int r = 0; r < 5; ++r) {
      int jo = r*4 + wv;
      int j = w*18 + jo;
      if (jo < 18 && j < NK) {
        int fam = (j < 64) ? 0 : (j < 64+nin ? 1 : 2);
        const float* kwr = KW + (size_t)j*300;
        float a = 0;
        for (int c = ln; c < 300; c += 64) a += vl[fam*300+c]*tanhf_(qWl[fam*300+c] + kwr[c]);
        a = wsum(a);
        if (ln==0) scb[j] = a;
      }
    }
    gbar(bar, (++phase)*NWD);
    // ---- PC: per-family softmax (redundant) + cell1 ----
    for (int i = tid; i < NK; i += 256) scl[i] = scb[i];
    __syncthreads();
    {
      float m0=-1e30f, m1=-1e30f, m2=-1e30f;
      for (int j = tid; j < NK; j += 256) {
        float x = scl[j];
        if (j < 64) m0 = fmaxf(m0,x); else if (j < 64+nin) m1 = fmaxf(m1,x); else m2 = fmaxf(m2,x);
      }
      m0 = wmax(m0); m1 = wmax(m1); m2 = wmax(m2);
      if (ln==0){ wr0[wv]=m0; wr1[wv]=m1; wr2[wv]=m2; }
      __syncthreads();
      if (tid==0){
        rm[0]=fmaxf(fmaxf(wr0[0],wr0[1]),fmaxf(wr0[2],wr0[3]));
        rm[1]=fmaxf(fmaxf(wr1[0],wr1[1]),fmaxf(wr1[2],wr1[3]));
        rm[2]=fmaxf(fmaxf(wr2[0],wr2[1]),fmaxf(wr2[2],wr2[3]));
      }
      __syncthreads();
      float s0=0,s1=0,s2=0;
      for (int j = tid; j < NK; j += 256) {
        int f = (j<64)?0:(j<64+nin?1:2);
        float e = __expf(scl[j] - rm[f]);
        scl[j] = e;
        if (f==0) s0+=e; else if (f==1) s1+=e; else s2+=e;
      }
      s0=wsum(s0); s1=wsum(s1); s2=wsum(s2);
      if (ln==0){ wr0[wv]=s0; wr1[wv]=s1; wr2[wv]=s2; }
      __syncthreads();
      if (tid==0){
        rz[0]=wr0[0]+wr0[1]+wr0[2]+wr0[3];
        rz[1]=wr1[0]+wr1[1]+wr1[2]+wr1[3];
        rz[2]=wr2[0]+wr2[1]+wr2[2]+wr2[3];
      }
      __syncthreads();
      for (int j = tid; j < NK; j += 256) {
        int f = (j<64)?0:(j<64+nin?1:2);
        scl[j] /= rz[f];
      }
      __syncthreads();
    }
    { int j = w*18 + tid;
      if (tid < 18 && j < NK) Alog[(size_t)t*1024 + j] = scl[j]; }
    for (int r = 0; r < 5; ++r) {
      int o = r*4 + wv, k = o>>2, m = o&3;
      int row = w*5 + k + 300*m;
      const float* g1 = G1KT + (size_t)row*NK;
      float a = 0;
      for (int j = ln; j < NK; j += 64) a += scl[j]*g1[j];
      a = wsum(a);
      if (ln==0) zl[o] = a + Ew[(size_t)t*1200 + row] + pre1[o];
    }
    __syncthreads();
    if (tid < 5) {
      int d = w*5 + tid;
      float ii=zl[tid*4], ff=zl[tid*4+1], gg=zl[tid*4+2], oo=zl[tid*4+3];
      float cc = t ? c1l[tid] : c0[d];
      float cn = sigf(ff)*cc + sigf(ii)*tanhf_(gg);
      c1l[tid] = cn;
      h1b[d] = sigf(oo)*tanhf_(cn);
    }
    gbar(bar, (++phase)*NWD);
    // ---- PD: cell2 ----
    for (int i = tid; i < 300; i += 256) h1l[i] = h1b[i];
    __syncthreads();
    for (int r = 0; r < 5; ++r) {
      int o = r*4 + wv, k = o>>2, m = o&3;
      int row = w*5 + k + 300*m;
      const float* w1 = Wih1 + (size_t)row*300;
      float a = 0;
      for (int d = ln; d < 300; d += 64) a += h1l[d]*w1[d];
      a = wsum(a);
      if (ln==0) zl[o] = a + pre2[o];
    }
    __syncthreads();
    if (tid < 5) {
      int d = w*5 + tid;
      float ii=zl[tid*4], ff=zl[tid*4+1], gg=zl[tid*4+2], oo=zl[tid*4+3];
      float cc = t ? c2l[tid] : c0[d];
      float cn = sigf(ff)*cc + sigf(ii)*tanhf_(gg);
      c2l[tid] = cn;
      float hn = sigf(oo)*tanhf_(cn);
      h2b[d] = hn;
      H2log[(size_t)t*300 + d] = hn;
    }
    gbar(bar, (++phase)*NWD);
  }
}

// ---------------- batched transform: o63 = tanh(H2@T_h.T + A@G2K) ----------------
__global__ void k_ctxout(const float* __restrict__ H2, const float* __restrict__ Al,
                         const float* __restrict__ G2K, const float* __restrict__ tW,
                         float* __restrict__ o63, int NK)
{
  const int t = blockIdx.x;
  for (int r = threadIdx.x; r < 300; r += 256) {
    float a = 0;
    const float* tr = tW + (size_t)r*1200;
    for (int d = 0; d < 300; ++d) a += H2[(size_t)t*300 + d]*tr[d];
    for (int j = 0; j < NK; ++j) a += Al[(size_t)t*1024 + j]*G2K[(size_t)j*300 + r];
    o63[(size_t)t*300 + r] = tanhf_(a);
  }
}

__global__ void k_colpart(const float* __restrict__ o63, const float* __restrict__ colW,
                          float* __restrict__ t63)
{
  const int t = blockIdx.x;
  for (int e = threadIdx.x; e < 300; e += 256) {
    float a = 0;
    const float* w = colW + (size_t)e*300;
    for (int d = 0; d < 300; ++d) a += o63[(size_t)t*300 + d]*w[d];
    t63[(size_t)t*300 + e] = a;
  }
}

// ---------------- vocab + schema scores ----------------
__global__ void k_score(const float* __restrict__ o63, const float* __restrict__ t63,
                        const float* __restrict__ sqlW, const float* __restrict__ sqlb,
                        const float* __restrict__ SE1, float* __restrict__ Dout)
{
  const int v = blockIdx.x*256 + threadIdx.x;
  if (v >= VOUT) return;
  const int t0 = blockIdx.y*16;
  const int tn = (t0 + 16 <= 63) ? 16 : (63 - t0);
  float acc[16];
#pragma unroll
  for (int k = 0; k < 16; ++k) acc[k] = 0.f;
  if (v < VQ) {
    const float* w = sqlW + (size_t)v*300;
    for (int d = 0; d < 300; ++d) {
      float wv_ = w[d];
#pragma unroll
      for (int k = 0; k < 16; ++k) acc[k] += wv_ * o63[(size_t)(t0+k)*300 + d];
    }
    float b = sqlb[v];
    for (int k = 0; k < tn; ++k) Dout[(size_t)(t0+k)*VOUT + v] = acc[k] + b;
  } else {
    const float* w = SE1 + (size_t)(v - VQ)*300;
    for (int d = 0; d < 300; ++d) {
      float wv_ = w[d];
#pragma unroll
      for (int k = 0; k < 16; ++k) acc[k] += wv_ * t63[(size_t)(t0+k)*300 + d];
    }
    for (int k = 0; k < tn; ++k) Dout[(size_t)(t0+k)*VOUT + v] = acc[k];
  }
}

// ---------------- in-place log-softmax + first-occurrence argmax ----------------
__global__ void k_lsm(float* __restrict__ rows, int* __restrict__ amx)
{
  const int t = blockIdx.x, tid = threadIdx.x, wv = tid>>6, ln = tid&63;
  float* row = rows + (size_t)t*VOUT;
  __shared__ float rv[4], rs[4];
  __shared__ int ri[4];
  float m = -1e30f; int mi = VOUT;
  for (int j = tid; j < VOUT; j += 256) {
    float x = row[j];
    if (x > m) { m = x; mi = j; }
  }
#pragma unroll
  for (int o = 32; o; o >>= 1) {
    float om = __shfl_xor(m, o); int oi = __shfl_xor(mi, o);
    if (om > m || (om == m && oi < mi)) { m = om; mi = oi; }
  }
  if (ln == 0) { rv[wv] = m; ri[wv] = mi; }
  __syncthreads();
  if (tid == 0) {
    for (int k = 1; k < 4; ++k)
      if (rv[k] > rv[0] || (rv[k] == rv[0] && ri[k] < ri[0])) { rv[0]=rv[k]; ri[0]=ri[k]; }
    amx[t] = ri[0];
  }
  __syncthreads();
  const float M = rv[0];
  float s = 0;
  for (int j = tid; j < VOUT; j += 256) s += __expf(row[j] - M);
  s = wsum(s);
  if (ln == 0) rs[wv] = s;
  __syncthreads();
  const float L = M + logf(rs[0]+rs[1]+rs[2]+rs[3]);
  for (int j = tid; j < VOUT; j += 256) row[j] -= L;
}

// ---------------- build prev_out entry: [bos; embed(argmax)] ----------------
__global__ void k_amemb(const int* __restrict__ amx, const float* __restrict__ qemb,
                        const float* __restrict__ SE1, float* __restrict__ OHt)
{
  for (int i = threadIdx.x; i < 64*300; i += 256) {
    int r = i/300, d = i - r*300;
    const float* src;
    if (r == 0) src = qemb;
    else {
      int id = amx[r-1];
      src = (id < VQ) ? qemb + (size_t)id*300 : SE1 + (size_t)(id-VQ)*300;
    }
    OHt[i] = src[d];
  }
}

extern "C" void kernel_launch(void* const* d_in, const int* in_sizes, int n_in,
                              void* d_out, int out_size, void* d_ws, size_t ws_size,
                              hipStream_t stream)
{
  const float* utter = (const float*)d_in[0];
  const float* qemb  = (const float*)d_in[1];
  const float* temb  = (const float*)d_in[2];
  const float* eWih  = (const float*)d_in[3];
  const float* eWhh  = (const float*)d_in[4];
  const float* eb    = (const float*)d_in[5];
  const float* aWq   = (const float*)d_in[6];
  const float* aWk   = (const float*)d_in[7];
  const float* av    = (const float*)d_in[8];
  const float* dWih0 = (const float*)d_in[9];
  const float* dWhh0 = (const float*)d_in[10];
  const float* db0   = (const float*)d_in[11];
  const float* dWih1 = (const float*)d_in[12];
  const float* dWhh1 = (const float*)d_in[13];
  const float* db1   = (const float*)d_in[14];
  const float* tW    = (const float*)d_in[15];
  const float* sqlW  = (const float*)d_in[16];
  const float* sqlb  = (const float*)d_in[17];
  const float* colW  = (const float*)d_in[18];
  const int* stok    = (const int*)d_in[19];
  const int* iseq    = (const int*)d_in[20];
  const int* ogt     = (const int*)d_in[21];
  float* dout = (float*)d_out;

  float* base = (float*)d_ws;
  size_t off = 0;
  auto A = [&](size_t n)->float*{ float* r = base + off; off += (n + 63) & ~(size_t)63; return r; };
  float* SE   = A(7*64*300);        // schema emb states: SE[i] before turn i's update
  float* XH   = A(5*128*300);       // x history (keys_in)
  float* OH   = A(5*64*300);        // output history (keys_out)
  float* HH   = A(5*300);
  float* CH   = A(5*300);
  float* xb   = A(128*300);
  float* ys1  = A(128*300);
  float* ys2  = A(128*300);
  float* Xg   = A(128*1200);
  float* fh   = A(320);
  float* fc   = A(320);
  float* fhs  = A(320);
  float* fcs  = A(320);
  float* h0b  = A(320);
  float* c0b  = A(320);
  float* h1b  = A(320);
  float* h2b  = A(320);
  float* qWb  = A(960);
  float* scb  = A(1024);
  float* KW   = A(1024*300);
  float* G1K  = A(1024*1200);
  float* G1KT = A(1200*1024);
  float* G2K  = A(1024*300);
  float* EwB  = A(63*1200);
  float* Alog = A(63*1024);
  float* H2lg = A(63*300);
  float* o63  = A(63*300);
  float* t63  = A(63*300);
  A(512);                            // OOB-read pad for k_score's full-16 unroll
  float* WqT  = A(4*300*300);
  float* WhhT = A(6*150*600);
  int* amx = (int*)A(64);
  int* bar = (int*)A(64);
  (void)ws_size; (void)in_sizes; (void)n_in; (void)out_size;

  dim3 B256(256);
  // setup: transposes + schema column encoder
  for (int k = 0; k < 4; ++k)
    k_transpose<<<dim3(10,10), B256, 0, stream>>>(aWq + (size_t)k*90000, WqT + (size_t)k*90000, 300, 300);
  for (int m = 0; m < 6; ++m)
    k_transpose<<<dim3(5,19), B256, 0, stream>>>(eWhh + (size_t)m*90000, WhhT + (size_t)m*90000, 600, 150);
  k_schema<<<128, B256, 0, stream>>>(temb, stok, eWih, eWhh, eb, SE);

  for (int i = 0; i < NTURNS; ++i) {
    const int kin  = (i+1 < MAXK) ? (i+1) : MAXK;
    const int kout = (i < MAXK) ? i : MAXK;
    const int nin = kin*128, nout = kout*64;
    const int NK = 64 + nin + nout;
    float* SEi = SE + (size_t)i*19200;
    float* SEo = SE + (size_t)(i+1)*19200;

    k_embed_in<<<75, B256, 0, stream>>>(utter, SEi, iseq + i*INLEN, xb);
    k_gemm_xg<<<dim3(5,8), B256, 0, stream>>>(xb,  eWih + 360000, eb + 1200, Xg);
    k_rec<<<2, 640, 0, stream>>>(Xg, WhhT + 180000, ys1, fhs, fcs);
    k_gemm_xg<<<dim3(5,8), B256, 0, stream>>>(ys1, eWih + 720000, eb + 2400, Xg);
    k_rec<<<2, 640, 0, stream>>>(Xg, WhhT + 360000, ys2, fh, fc);
    k_schema_upd<<<64, B256, 0, stream>>>(SEi, ys2, SEo);
    k_h0c0<<<61, B256, 0, stream>>>(fh, fc, HH, CH, XH, ys2, aWq, aWk, av, h0b, c0b, i, bar);
    k_kw <<<NK, B256, 0, stream>>>(SEo, XH, OH, aWk, KW, nin, nout);
    k_g1k<<<NK, B256, 0, stream>>>(SEo, XH, OH, dWih0, G1K, nin, nout);
    k_g2k<<<NK, B256, 0, stream>>>(SEo, XH, OH, tW, G2K, nin, nout);
    k_ew<<<63, B256, 0, stream>>>(ogt + i*64, qemb, SEo, dWih0, db0, EwB);
    k_transpose<<<dim3(38, (NK+31)/32), B256, 0, stream>>>(G1K, G1KT, NK, 1200);
    k_dec<<<NWD, B256, 0, stream>>>(KW, G1KT, EwB, WqT, av, dWhh0, dWih1, dWhh1, db1,
                                    h0b, c0b, h1b, h2b, qWb, scb, Alog, H2lg, nin, nout, bar);
    k_ctxout<<<63, B256, 0, stream>>>(H2lg, Alog, G2K, tW, o63, NK);
    k_colpart<<<63, B256, 0, stream>>>(o63, colW, t63);
    k_score<<<dim3(118,4), B256, 0, stream>>>(o63, t63, sqlW, sqlb, SEo, dout + (size_t)i*63*VOUT);
    k_lsm<<<63, B256, 0, stream>>>(dout + (size_t)i*63*VOUT, amx);
    if (i < MAXK)
      k_amemb<<<1, B256, 0, stream>>>(amx, qemb, SEo, OH + (size_t)i*19200);
  }
}

// Round 2
// 18692.668 us; speedup vs baseline: 1.3219x; 1.3219x over previous
//
#include <hip/hip_runtime.h>

#define EMB 300
#define VU 50000
#define VQ 30000
#define NCOLS 64
#define COLLEN 6
#define NTURNS 6
#define INLEN 128
#define TSTEPS 63
#define VOUT 30064
#define MAXK 5
#define NWD 60

__device__ __forceinline__ float sigf(float x){ return 1.0f/(1.0f+__expf(-x)); }
__device__ __forceinline__ float tanhf_(float x){ return 1.0f - 2.0f/(1.0f+__expf(2.0f*x)); }
__device__ __forceinline__ float wsum(float v){
#pragma unroll
  for (int o=32;o;o>>=1) v += __shfl_xor(v,o);
  return v;
}
__device__ __forceinline__ float wmax(float v){
#pragma unroll
  for (int o=32;o;o>>=1) v = fmaxf(v,__shfl_xor(v,o));
  return v;
}

// cache-bypassing (agent-scope) float load/store for cross-WG exchange
__device__ __forceinline__ void gstore(float* p, float v){
  __hip_atomic_store((int*)p, __float_as_int(v), __ATOMIC_RELAXED, __HIP_MEMORY_SCOPE_AGENT);
}
__device__ __forceinline__ float gload(const float* p){
  return __int_as_float(__hip_atomic_load((const int*)p, __ATOMIC_RELAXED, __HIP_MEMORY_SCOPE_AGENT));
}

// flag-based global barrier: arrive = drain own vmem + store flag; wait = wave0 sweeps all flags
__device__ __forceinline__ void garrive(int* flags, int w, int P){
  asm volatile("s_waitcnt vmcnt(0)" ::: "memory");
  __syncthreads();
  if (threadIdx.x == 0)
    __hip_atomic_store(flags + w, P, __ATOMIC_RELAXED, __HIP_MEMORY_SCOPE_AGENT);
}
__device__ __forceinline__ void gwait(const int* flags, int P){
  if (threadIdx.x < 64) {
    int v;
    do {
      v = (threadIdx.x < NWD) ? __hip_atomic_load(flags + threadIdx.x, __ATOMIC_RELAXED, __HIP_MEMORY_SCOPE_AGENT) : P;
    } while (__any(v < P));
  }
  __syncthreads();
}

__global__ void k_init(int* flags){ if (threadIdx.x < 64) flags[threadIdx.x] = 0; }

// ---------------- batched transpose: out[c][r] = in[r][c], z = matrix index ----------------
__global__ void k_transposeB(const float* __restrict__ in, float* __restrict__ out,
                             int R, int C, size_t mstride)
{
  __shared__ float tile[32][33];
  const float* inp = in + (size_t)blockIdx.z*mstride;
  float* outp = out + (size_t)blockIdx.z*mstride;
  const int rb = blockIdx.y*32, cb = blockIdx.x*32;
  const int tx = threadIdx.x & 31, ty = threadIdx.x >> 5;
  for (int k = 0; k < 32; k += 8) {
    int r = rb + ty + k, c = cb + tx;
    if (r < R && c < C) tile[ty+k][tx] = inp[(size_t)r*C + c];
  }
  __syncthreads();
  for (int k = 0; k < 32; k += 8) {
    int c = cb + ty + k, r = rb + tx;
    if (c < C && r < R) outp[(size_t)c*R + r] = tile[tx][ty+k];
  }
}

// ---------------- schema column BiLSTM (layer 0), one WG per (col,dir) ----------------
__global__ void k_schema(const float* __restrict__ temb, const int* __restrict__ stok,
                         const float* __restrict__ Wih, const float* __restrict__ Whh,
                         const float* __restrict__ bb, float* __restrict__ SE0)
{
  const int col = blockIdx.x >> 1, dir = blockIdx.x & 1, tid = threadIdx.x;
  __shared__ float hl[150], cl[150], zl[600];
  if (tid < 150) { hl[tid]=0.f; cl[tid]=0.f; }
  __syncthreads();
  const float* Wi = Wih + (size_t)dir*600*300;
  const float* Wh = Whh + (size_t)dir*600*150;
  const float* bd = bb + dir*600;
  for (int s = 0; s < COLLEN; ++s) {
    const int pos = dir ? (COLLEN-1-s) : s;
    const int tok = stok[col*COLLEN + pos];
    const float* x = temb + (size_t)tok*300;
    for (int g = tid; g < 600; g += 256) {
      float a = bd[g];
      const float* wi = Wi + (size_t)g*300;
      for (int c = 0; c < 300; ++c) a += x[c]*wi[c];
      const float* wh = Wh + (size_t)g*150;
      for (int j = 0; j < 150; ++j) a += hl[j]*wh[j];
      zl[g] = a;
    }
    __syncthreads();
    if (tid < 150) {
      float ii=zl[tid], ff=zl[150+tid], gg=zl[300+tid], oo=zl[450+tid];
      float cn = sigf(ff)*cl[tid] + sigf(ii)*tanhf_(gg);
      cl[tid]=cn; hl[tid]=sigf(oo)*tanhf_(cn);
    }
    __syncthreads();
  }
  if (tid < 150) SE0[(size_t)col*300 + dir*150 + tid] = hl[tid];
}

// ---------------- Xg[pos][g] = embed/x [pos] @ Wih.T + b (1200 gates, fused embedding) -------
__global__ void k_gemm_xe(const float* __restrict__ src, const float* __restrict__ SEi,
                          const int* __restrict__ iseq, int mode,
                          const float* __restrict__ WihL, const float* __restrict__ bL,
                          float* __restrict__ Xg)
{
  const int g = blockIdx.x*256 + threadIdx.x;
  if (g >= 1200) return;
  const int p0 = blockIdx.y*16;
  const float* xr[16];
#pragma unroll
  for (int t = 0; t < 16; ++t) {
    int p = p0 + t;
    if (mode) xr[t] = src + (size_t)p*300;
    else {
      int tok = iseq[p];
      xr[t] = (tok < VU) ? src + (size_t)tok*300 : SEi + (size_t)(tok - VU)*300;
    }
  }
  const float b = bL[g];
  const float* w = WihL + (size_t)g*300;
  float acc[16];
#pragma unroll
  for (int t = 0; t < 16; ++t) acc[t] = b;
  for (int c = 0; c < 300; ++c) {
    float wv = w[c];
#pragma unroll
    for (int t = 0; t < 16; ++t) acc[t] += wv * xr[t][c];
  }
#pragma unroll
  for (int t = 0; t < 16; ++t) Xg[(size_t)(p0+t)*1200 + g] = acc[t];
}

// ---------------- BiLSTM recurrence; grid=2 (fwd/bwd), Whh in VGPRs ----------------
__global__ __launch_bounds__(640) void k_rec(
    const float* __restrict__ Xg, const float* __restrict__ WhhTL,
    float* __restrict__ ys, float* __restrict__ fh, float* __restrict__ fc)
{
  const int dir = blockIdx.x, tid = threadIdx.x;
  __shared__ __align__(16) float hl[152];
  __shared__ float cl[152], zl[600];
  float w[150];
  const float* wt = WhhTL + (size_t)dir*150*600;
  if (tid < 600) {
#pragma unroll
    for (int j = 0; j < 150; ++j) w[j] = wt[(size_t)j*600 + tid];
  }
  if (tid < 152) { hl[tid] = 0.f; cl[tid] = 0.f; }
  __syncthreads();
  for (int s = 0; s < INLEN; ++s) {
    const int pos = dir ? (INLEN-1-s) : s;
    if (tid < 600) {
      float acc = Xg[(size_t)pos*1200 + dir*600 + tid];
      const float4* h4 = (const float4*)hl;
#pragma unroll
      for (int j4 = 0; j4 < 37; ++j4) {
        float4 h = h4[j4];
        acc += w[4*j4]*h.x + w[4*j4+1]*h.y + w[4*j4+2]*h.z + w[4*j4+3]*h.w;
      }
      acc += w[148]*hl[148] + w[149]*hl[149];
      zl[tid] = acc;
    }
    __syncthreads();
    if (tid < 150) {
      float ii=zl[tid], ff=zl[150+tid], gg=zl[300+tid], oo=zl[450+tid];
      float cn = sigf(ff)*cl[tid] + sigf(ii)*tanhf_(gg);
      cl[tid] = cn;
      float hn = sigf(oo)*tanhf_(cn);
      hl[tid] = hn;
      ys[(size_t)pos*300 + dir*150 + tid] = hn;
    }
    __syncthreads();
  }
  if (tid < 150) { fh[dir*150 + tid] = hl[tid]; fc[dir*150 + tid] = cl[tid]; }
}

// ---------------- schema update: SEo = SEi + softmax(SEi@ys2.T)@ys2 ----------------
__global__ void k_schema_upd(const float* __restrict__ SEi, const float* __restrict__ ys2,
                             float* __restrict__ SEo)
{
  const int row = blockIdx.x, tid = threadIdx.x;
  __shared__ float sl[300], al[128], red[4];
  for (int d = tid; d < 300; d += 256) sl[d] = SEi[(size_t)row*300 + d];
  __syncthreads();
  if (tid < 128) {
    float a = 0;
    const float* yr = ys2 + (size_t)tid*300;
    for (int d = 0; d < 300; ++d) a += sl[d]*yr[d];
    al[tid] = a;
  }
  __syncthreads();
  if (tid < 64) { float m = fmaxf(al[tid], al[tid+64]); m = wmax(m); if (tid==0) red[0]=m; }
  __syncthreads();
  if (tid < 128) al[tid] = __expf(al[tid] - red[0]);
  __syncthreads();
  if (tid < 64) { float s = al[tid] + al[tid+64]; s = wsum(s); if (tid==0) red[1]=s; }
  __syncthreads();
  const float invz = 1.0f/red[1];
  for (int d = tid; d < 300; d += 256) {
    float a = sl[d];
    for (int j = 0; j < 128; ++j) a += (al[j]*invz) * ys2[(size_t)j*300 + d];
    SEo[(size_t)row*300 + d] = a;
  }
}

// ---------------- history append (turn < MAXK only) ----------------
__global__ void k_hist(const float* __restrict__ fh, const float* __restrict__ fc,
                       const float* __restrict__ ys2,
                       float* __restrict__ HH, float* __restrict__ CH,
                       float* __restrict__ XH, int turn)
{
  const int tid = threadIdx.x;
  for (int i = blockIdx.x*256 + tid; i < INLEN*300; i += 60*256)
    XH[(size_t)turn*INLEN*300 + i] = ys2[i];
  if (blockIdx.x == 0)
    for (int d = tid; d < 300; d += 256) { HH[turn*300+d] = fh[d]; CH[turn*300+d] = fc[d]; }
}

// ---------------- per-turn key tables (kw | g1k | g2k | ew fused) ----------------
__device__ __forceinline__ const float* key_ptr(int j, int nin, const float* SE1,
                                                const float* XH, const float* OH, int* fam)
{
  if (j < 64) { *fam = 0; return SE1 + (size_t)j*300; }
  if (j < 64+nin) { *fam = 1; return XH + (size_t)(j-64)*300; }
  *fam = 2; return OH + (size_t)(j-64-nin)*300;
}

__global__ void k_tables(const float* __restrict__ SE1, const float* __restrict__ XH,
                         const float* __restrict__ OH, const float* __restrict__ Wk,
                         const float* __restrict__ Wih0, const float* __restrict__ b0,
                         const float* __restrict__ tW, const float* __restrict__ qemb,
                         const int* __restrict__ gt,
                         float* __restrict__ KW, float* __restrict__ G1K,
                         float* __restrict__ G2K, float* __restrict__ Ew,
                         int nin, int nout)
{
  const int NK = 64 + nin + nout;
  const int b = blockIdx.x;
  if (b < NK) {
    int fam; const float* Kr = key_ptr(b, nin, SE1, XH, OH, &fam);
    const float* W = Wk + (size_t)(1+fam)*90000;
    for (int c = threadIdx.x; c < 300; c += 256) {
      float a = 0;
      for (int d = 0; d < 300; ++d) a += Kr[d]*W[(size_t)d*300 + c];
      KW[(size_t)b*300 + c] = a;
    }
  } else if (b < 2*NK) {
    int j = b - NK;
    int fam; const float* Kr = key_ptr(j, nin, SE1, XH, OH, &fam);
    const int cb = 300 + fam*300;
    for (int r = threadIdx.x; r < 1200; r += 256) {
      float a = 0;
      const float* wp = Wih0 + (size_t)r*1200 + cb;
      for (int c = 0; c < 300; ++c) a += Kr[c]*wp[c];
      G1K[(size_t)j*1200 + r] = a;
    }
  } else if (b < 3*NK) {
    int j = b - 2*NK;
    int fam; const float* Kr = key_ptr(j, nin, SE1, XH, OH, &fam);
    const int cb = 300 + fam*300;
    for (int r = threadIdx.x; r < 300; r += 256) {
      float a = 0;
      const float* wp = tW + (size_t)r*1200 + cb;
      for (int c = 0; c < 300; ++c) a += Kr[c]*wp[c];
      G2K[(size_t)j*300 + r] = a;
    }
  } else {
    int t = b - 3*NK;
    int tok = gt[t];
    const float* e = (tok < VQ) ? qemb + (size_t)tok*300 : SE1 + (size_t)(tok-VQ)*300;
    for (int r = threadIdx.x; r < 1200; r += 256) {
      float a = b0[r];
      const float* wp = Wih0 + (size_t)r*1200;
      for (int c = 0; c < 300; ++c) a += e[c]*wp[c];
      Ew[(size_t)t*1200 + r] = a;
    }
  }
}

// ---------------- persistent decoder: 60 WGs, LDS/reg-resident, flag barriers ----------------
__global__ __launch_bounds__(256, 1) void k_dec(
    const float* __restrict__ KW, const float* __restrict__ G1KT,
    const float* __restrict__ Ew, const float* __restrict__ WqT,
    const float* __restrict__ av, const float* __restrict__ Wq0,
    const float* __restrict__ Wk0,
    const float* __restrict__ Whh0, const float* __restrict__ Wih1,
    const float* __restrict__ Whh1, const float* __restrict__ b1,
    const float* __restrict__ fh, const float* __restrict__ fc,
    const float* __restrict__ HH, const float* __restrict__ CH,
    float* __restrict__ h0b, float* __restrict__ c0b,
    float* __restrict__ h1b, float* __restrict__ h2b,
    float* __restrict__ qWb, float* __restrict__ scb,
    float* __restrict__ Alog, float* __restrict__ H2log,
    int nin, int nout, int turn, int* __restrict__ flags)
{
  const int NK = 64 + nin + nout;
  const int w = blockIdx.x, tid = threadIdx.x;
  const int wv = tid >> 6, ln = tid & 63;
  __shared__ float g1kl[20][1024];          // 80 KB: this WG's 20 gate rows x NK
  __shared__ float kwl[18][320];            // this WG's 18 keys' kW rows (padded)
  __shared__ float qWlp[3][320];            // per-family padded qW
  __shared__ float vllp[3][320];            // per-family padded v
  __shared__ float ewl[63][20];             // Ew slice
  __shared__ float scl[1024];
  __shared__ float dhl[320], h1l[320];
  __shared__ float pre1[20], pre2[20], zl[20], c1l[5], c2l[5];
  __shared__ float redA[4], alscA[8];
  __shared__ float wr0[4], wr1[4], wr2[4], rm[3], rz[3];
  int P = turn * 253;

  // ---- LDS preloads (fence-immune residency) ----
  for (int i = tid; i < 20*1024; i += 256) {
    int o = i >> 10, j = i & 1023;
    int row = w*5 + (o % 5) + 300*(o / 5);
    g1kl[o][j] = (j < NK) ? G1KT[(size_t)row*NK + j] : 0.f;
  }
  for (int i = tid; i < 18*320; i += 256) {
    int jo = i / 320, c = i - jo*320;
    int j = w*18 + jo;
    kwl[jo][c] = (c < 300 && j < NK) ? KW[(size_t)j*300 + c] : 0.f;
  }
  for (int i = tid; i < 3*320; i += 256) {
    int f = i / 320, c = i - f*320;
    vllp[f][c] = (c < 300) ? av[300 + f*300 + c] : 0.f;
    qWlp[f][c] = 0.f;
  }
  for (int i = tid; i < 63*20; i += 256) {
    int t = i / 20, o = i - t*20;
    int row = w*5 + (o % 5) + 300*(o / 5);
    ewl[t][o] = Ew[(size_t)t*1200 + row];
  }
  if (tid < 20) { dhl[300+tid] = 0.f; h1l[300+tid] = 0.f; }

  // ---- register preloads ----
  float rwh0[5][5], rwh1[5][5], rwi1[5][5], rwq4[4][5], b1r[5];
#pragma unroll
  for (int r = 0; r < 5; ++r) {
    int row = w*5 + r + 300*wv;
    b1r[r] = b1[row];
#pragma unroll
    for (int k = 0; k < 5; ++k) {
      int d = ln + 64*k;
      rwh0[r][k] = (d < 300) ? Whh0[(size_t)row*300 + d] : 0.f;
      rwh1[r][k] = (d < 300) ? Whh1[(size_t)row*300 + d] : 0.f;
      rwi1[r][k] = (d < 300) ? Wih1[(size_t)row*300 + d] : 0.f;
    }
  }
#pragma unroll
  for (int r = 0; r < 4; ++r) {
    int o = r*4 + wv;
    int q = w*15 + ((o < 15) ? o : 0);
    int fam = q / 300, c = q - fam*300;
    const float* bp = WqT + ((size_t)(1+fam)*300 + c)*300;
#pragma unroll
    for (int k = 0; k < 5; ++k) {
      int d = ln + 64*k;
      rwq4[r][k] = (o < 15 && d < 300) ? bp[d] : 0.f;
    }
  }
  __syncthreads();

  // ---- prologue: WG0 computes h0/c0 (history attention); others already preloaded ----
  if (w == 0) {
    if (turn == 0) {
      for (int d = tid; d < 300; d += 256) { gstore(h0b+d, fh[d]); gstore(c0b+d, fc[d]); }
    } else {
      const int nh = turn;
      for (int d = tid; d < 300; d += 256) dhl[d] = fh[d];
      __syncthreads();
      for (int rep = 0; rep < 2; ++rep) {
        const float* keys = rep ? CH : HH;
        for (int c = tid; c < 300; c += 256) {
          float a = 0;
          for (int d = 0; d < 300; ++d) a += dhl[d]*Wq0[(size_t)d*300 + c];
          h1l[c] = a;
        }
        __syncthreads();
        for (int k = 0; k < nh; ++k) {
          const float* Kr = keys + (size_t)k*300;
          float part = 0;
          for (int c = tid; c < 300; c += 256) {
            float kw = 0;
            for (int d = 0; d < 300; ++d) kw += Kr[d]*Wk0[(size_t)d*300 + c];
            part += av[c]*tanhf_(h1l[c] + kw);
          }
          part = wsum(part);
          if (ln == 0) redA[wv] = part;
          __syncthreads();
          if (tid == 0) alscA[k] = redA[0]+redA[1]+redA[2]+redA[3];
          __syncthreads();
        }
        if (tid == 0) {
          float m = -1e30f;
          for (int k = 0; k < nh; ++k) m = fmaxf(m, alscA[k]);
          float z = 0;
          for (int k = 0; k < nh; ++k) { alscA[k] = __expf(alscA[k]-m); z += alscA[k]; }
          for (int k = 0; k < nh; ++k) alscA[k] /= z;
        }
        __syncthreads();
        if (rep == 0) {
          for (int c = tid; c < 300; c += 256) {
            float a = dhl[c];
            for (int k = 0; k < nh; ++k) a += alscA[k]*keys[(size_t)k*300 + c];
            scl[c] = a; gstore(h0b+c, a);
          }
          __syncthreads();
          for (int d = tid; d < 300; d += 256) dhl[d] = fc[d];
          __syncthreads();
        } else {
          for (int c = tid; c < 300; c += 256) {
            float a = scl[c];
            for (int k = 0; k < nh; ++k) a += alscA[k]*keys[(size_t)k*300 + c];
            gstore(c0b+c, a);
          }
        }
      }
    }
  }
  garrive(flags, w, ++P);
  gwait(flags, P);

  // ---- init decoder states ----
  for (int i = tid; i < 300; i += 256) { float v = gload(h0b+i); dhl[i] = v; h1l[i] = v; }
  if (tid < 5) { float v = gload(c0b + w*5 + tid); c1l[tid] = v; c2l[tid] = v; }
  __syncthreads();

  for (int t = 0; t < TSTEPS; ++t) {
    // ---- PA: qW slice + Whh0/Whh1 pre-gates (all reg/LDS) ----
    if (t) {
      for (int i = tid; i < 300; i += 256) dhl[i] = gload(h2b+i);
      __syncthreads();
    }
#pragma unroll
    for (int r = 0; r < 4; ++r) {
      float a = 0;
#pragma unroll
      for (int k = 0; k < 5; ++k) a += rwq4[r][k]*dhl[ln + 64*k];
      a = wsum(a);
      int o = r*4 + wv;
      if (ln == 0 && o < 15) gstore(qWb + w*15 + o, a);
    }
#pragma unroll
    for (int r = 0; r < 5; ++r) {
      float a1 = 0, a2 = 0;
#pragma unroll
      for (int k = 0; k < 5; ++k) {
        float hv = h1l[ln + 64*k], dv = dhl[ln + 64*k];
        a1 += rwh0[r][k]*hv; a2 += rwh1[r][k]*dv;
      }
      a1 = wsum(a1); a2 = wsum(a2);
      if (ln == 0) { pre1[wv*5+r] = a1; pre2[wv*5+r] = a2 + b1r[r]; }
    }
    garrive(flags, w, ++P); gwait(flags, P);

    // ---- PB: attention scores ----
    for (int i = tid; i < 900; i += 256) {
      int f = i / 300, c = i - f*300;
      qWlp[f][c] = gload(qWb + i);
    }
    __syncthreads();
#pragma unroll
    for (int r = 0; r < 5; ++r) {
      int jo = wv*5 + r;
      int j = w*18 + jo;
      bool va = (jo < 18) && (j < NK);
      int f = va ? ((j < 64) ? 0 : (j < 64+nin ? 1 : 2)) : 0;
      int jc = (jo < 18) ? jo : 0;
      float a = 0;
#pragma unroll
      for (int k = 0; k < 5; ++k) {
        int c = ln + 64*k;
        a += vllp[f][c] * tanhf_(qWlp[f][c] + kwl[jc][c]);
      }
      a = wsum(a);
      if (ln == 0 && va) gstore(scb + j, a);
    }
    garrive(flags, w, ++P); gwait(flags, P);

    // ---- PC: per-family softmax (redundant) + ctx + cell1 ----
    for (int i = tid; i < NK; i += 256) scl[i] = gload(scb + i);
    __syncthreads();
    {
      float m0=-1e30f, m1=-1e30f, m2=-1e30f;
      for (int j = tid; j < NK; j += 256) {
        float x = scl[j];
        if (j < 64) m0 = fmaxf(m0,x); else if (j < 64+nin) m1 = fmaxf(m1,x); else m2 = fmaxf(m2,x);
      }
      m0 = wmax(m0); m1 = wmax(m1); m2 = wmax(m2);
      if (ln==0){ wr0[wv]=m0; wr1[wv]=m1; wr2[wv]=m2; }
      __syncthreads();
      if (tid==0){
        rm[0]=fmaxf(fmaxf(wr0[0],wr0[1]),fmaxf(wr0[2],wr0[3]));
        rm[1]=fmaxf(fmaxf(wr1[0],wr1[1]),fmaxf(wr1[2],wr1[3]));
        rm[2]=fmaxf(fmaxf(wr2[0],wr2[1]),fmaxf(wr2[2],wr2[3]));
      }
      __syncthreads();
      float s0=0,s1=0,s2=0;
      for (int j = tid; j < NK; j += 256) {
        int f = (j<64)?0:(j<64+nin?1:2);
        float e = __expf(scl[j] - rm[f]);
        scl[j] = e;
        if (f==0) s0+=e; else if (f==1) s1+=e; else s2+=e;
      }
      s0=wsum(s0); s1=wsum(s1); s2=wsum(s2);
      if (ln==0){ wr0[wv]=s0; wr1[wv]=s1; wr2[wv]=s2; }
      __syncthreads();
      if (tid==0){
        rz[0]=wr0[0]+wr0[1]+wr0[2]+wr0[3];
        rz[1]=wr1[0]+wr1[1]+wr1[2]+wr1[3];
        rz[2]=wr2[0]+wr2[1]+wr2[2]+wr2[3];
      }
      __syncthreads();
      for (int j = tid; j < NK; j += 256) {
        int f = (j<64)?0:(j<64+nin?1:2);
        scl[j] /= rz[f];
      }
      __syncthreads();
    }
    if (tid < 18) { int j = w*18 + tid; if (j < NK) Alog[(size_t)t*1024 + j] = scl[j]; }
    {
      const int KC = NK >> 6;
#pragma unroll 1
      for (int r = 0; r < 5; ++r) {
        int o = wv*5 + r;
        float a = 0;
        for (int k = 0; k < KC; ++k) { int j = ln + 64*k; a += scl[j]*g1kl[o][j]; }
        a = wsum(a);
        if (ln == 0) zl[o] = a + ewl[t][o] + pre1[o];
      }
    }
    __syncthreads();
    if (tid < 5) {
      float ii=zl[tid], ff=zl[5+tid], gg=zl[10+tid], oo=zl[15+tid];
      float cn = sigf(ff)*c1l[tid] + sigf(ii)*tanhf_(gg);
      c1l[tid] = cn;
      gstore(h1b + w*5 + tid, sigf(oo)*tanhf_(cn));
    }
    garrive(flags, w, ++P); gwait(flags, P);

    // ---- PD: cell2 ----
    for (int i = tid; i < 300; i += 256) h1l[i] = gload(h1b + i);
    __syncthreads();
#pragma unroll
    for (int r = 0; r < 5; ++r) {
      float a = 0;
#pragma unroll
      for (int k = 0; k < 5; ++k) a += rwi1[r][k]*h1l[ln + 64*k];
      a = wsum(a);
      if (ln == 0) zl[wv*5+r] = a + pre2[wv*5+r];
    }
    __syncthreads();
    if (tid < 5) {
      int d = w*5 + tid;
      float ii=zl[tid], ff=zl[5+tid], gg=zl[10+tid], oo=zl[15+tid];
      float cn = sigf(ff)*c2l[tid] + sigf(ii)*tanhf_(gg);
      c2l[tid] = cn;
      float hn = sigf(oo)*tanhf_(cn);
      gstore(h2b + d, hn);
      H2log[(size_t)t*300 + d] = hn;
    }
    garrive(flags, w, ++P); gwait(flags, P);
  }
}

// ---------------- fused: o63 = tanh(H2@T.T + A@G2K); t63 = o63@colW.T ----------------
__global__ void k_ctxout2(const float* __restrict__ H2, const float* __restrict__ Al,
                          const float* __restrict__ G2K, const float* __restrict__ tW,
                          const float* __restrict__ colW,
                          float* __restrict__ o63, float* __restrict__ t63, int NK)
{
  const int t = blockIdx.x, tid = threadIdx.x;
  __shared__ float ol[304], h2l[304];
  for (int d = tid; d < 300; d += 256) h2l[d] = H2[(size_t)t*300 + d];
  __syncthreads();
  for (int r = tid; r < 300; r += 256) {
    float a = 0;
    const float* tr = tW + (size_t)r*1200;
    for (int d = 0; d < 300; ++d) a += h2l[d]*tr[d];
    for (int j = 0; j < NK; ++j) a += Al[(size_t)t*1024 + j]*G2K[(size_t)j*300 + r];
    float v = tanhf_(a);
    ol[r] = v;
    o63[(size_t)t*300 + r] = v;
  }
  __syncthreads();
  for (int e = tid; e < 300; e += 256) {
    float a = 0;
    const float* wc = colW + (size_t)e*300;
    for (int d = 0; d < 300; ++d) a += ol[d]*wc[d];
    t63[(size_t)t*300 + e] = a;
  }
}

// ---------------- vocab + schema scores ----------------
__global__ void k_score(const float* __restrict__ o63, const float* __restrict__ t63,
                        const float* __restrict__ sqlW, const float* __restrict__ sqlb,
                        const float* __restrict__ SE1, float* __restrict__ Dout)
{
  const int v = blockIdx.x*256 + threadIdx.x;
  if (v >= VOUT) return;
  const int t0 = blockIdx.y*16;
  const int tn = (t0 + 16 <= 63) ? 16 : (63 - t0);
  float acc[16];
#pragma unroll
  for (int k = 0; k < 16; ++k) acc[k] = 0.f;
  if (v < VQ) {
    const float* w = sqlW + (size_t)v*300;
    for (int d = 0; d < 300; ++d) {
      float wv_ = w[d];
#pragma unroll
      for (int k = 0; k < 16; ++k) acc[k] += wv_ * o63[(size_t)(t0+k)*300 + d];
    }
    float b = sqlb[v];
    for (int k = 0; k < tn; ++k) Dout[(size_t)(t0+k)*VOUT + v] = acc[k] + b;
  } else {
    const float* w = SE1 + (size_t)(v - VQ)*300;
    for (int d = 0; d < 300; ++d) {
      float wv_ = w[d];
#pragma unroll
      for (int k = 0; k < 16; ++k) acc[k] += wv_ * t63[(size_t)(t0+k)*300 + d];
    }
    for (int k = 0; k < tn; ++k) Dout[(size_t)(t0+k)*VOUT + v] = acc[k];
  }
}

// ---------------- in-place log-softmax + first-occurrence argmax ----------------
__global__ void k_lsm(float* __restrict__ rows, int* __restrict__ amx)
{
  const int t = blockIdx.x, tid = threadIdx.x, wv = tid>>6, ln = tid&63;
  float* row = rows + (size_t)t*VOUT;
  __shared__ float rv[4], rs[4];
  __shared__ int ri[4];
  float m = -1e30f; int mi = VOUT;
  for (int j = tid; j < VOUT; j += 256) {
    float x = row[j];
    if (x > m) { m = x; mi = j; }
  }
#pragma unroll
  for (int o = 32; o; o >>= 1) {
    float om = __shfl_xor(m, o); int oi = __shfl_xor(mi, o);
    if (om > m || (om == m && oi < mi)) { m = om; mi = oi; }
  }
  if (ln == 0) { rv[wv] = m; ri[wv] = mi; }
  __syncthreads();
  if (tid == 0) {
    for (int k = 1; k < 4; ++k)
      if (rv[k] > rv[0] || (rv[k] == rv[0] && ri[k] < ri[0])) { rv[0]=rv[k]; ri[0]=ri[k]; }
    amx[t] = ri[0];
  }
  __syncthreads();
  const float M = rv[0];
  float s = 0;
  for (int j = tid; j < VOUT; j += 256) s += __expf(row[j] - M);
  s = wsum(s);
  if (ln == 0) rs[wv] = s;
  __syncthreads();
  const float L = M + logf(rs[0]+rs[1]+rs[2]+rs[3]);
  for (int j = tid; j < VOUT; j += 256) row[j] -= L;
}

// ---------------- build prev_out entry: [bos; embed(argmax)] ----------------
__global__ void k_amemb(const int* __restrict__ amx, const float* __restrict__ qemb,
                        const float* __restrict__ SE1, float* __restrict__ OHt)
{
  for (int i = threadIdx.x; i < 64*300; i += 256) {
    int r = i/300, d = i - r*300;
    const float* src;
    if (r == 0) src = qemb;
    else {
      int id = amx[r-1];
      src = (id < VQ) ? qemb + (size_t)id*300 : SE1 + (size_t)(id-VQ)*300;
    }
    OHt[i] = src[d];
  }
}

extern "C" void kernel_launch(void* const* d_in, const int* in_sizes, int n_in,
                              void* d_out, int out_size, void* d_ws, size_t ws_size,
                              hipStream_t stream)
{
  const float* utter = (const float*)d_in[0];
  const float* qemb  = (const float*)d_in[1];
  const float* temb  = (const float*)d_in[2];
  const float* eWih  = (const float*)d_in[3];
  const float* eWhh  = (const float*)d_in[4];
  const float* eb    = (const float*)d_in[5];
  const float* aWq   = (const float*)d_in[6];
  const float* aWk   = (const float*)d_in[7];
  const float* av    = (const float*)d_in[8];
  const float* dWih0 = (const float*)d_in[9];
  const float* dWhh0 = (const float*)d_in[10];
  const float* db0   = (const float*)d_in[11];
  const float* dWih1 = (const float*)d_in[12];
  const float* dWhh1 = (const float*)d_in[13];
  const float* db1   = (const float*)d_in[14];
  const float* tW    = (const float*)d_in[15];
  const float* sqlW  = (const float*)d_in[16];
  const float* sqlb  = (const float*)d_in[17];
  const float* colW  = (const float*)d_in[18];
  const int* stok    = (const int*)d_in[19];
  const int* iseq    = (const int*)d_in[20];
  const int* ogt     = (const int*)d_in[21];
  float* dout = (float*)d_out;

  float* base = (float*)d_ws;
  size_t off = 0;
  auto A = [&](size_t n)->float*{ float* r = base + off; off += (n + 63) & ~(size_t)63; return r; };
  float* SE   = A(7*64*300);
  float* XH   = A(5*128*300);
  float* OH   = A(5*64*300);
  float* HH   = A(5*300);
  float* CH   = A(5*300);
  float* ys1  = A(128*300);
  float* ys2  = A(128*300);
  float* Xg   = A(128*1200);
  float* fh   = A(320);
  float* fc   = A(320);
  float* fhs  = A(320);
  float* fcs  = A(320);
  float* h0b  = A(320);
  float* c0b  = A(320);
  float* h1b  = A(320);
  float* h2b  = A(320);
  float* qWb  = A(960);
  float* scb  = A(1024);
  float* KW   = A(1024*300);
  float* G1K  = A(1024*1200);
  float* G1KT = A(1200*1024);
  float* G2K  = A(1024*300);
  float* EwB  = A(63*1200);
  float* Alog = A(63*1024);
  float* H2lg = A(64*300);
  float* o63  = A(64*300);
  float* t63  = A(64*300);
  A(512);
  float* WqT  = A(4*300*300);
  float* WhhT = A(6*150*600);
  int* amx   = (int*)A(64);
  int* flags = (int*)A(64);
  (void)ws_size; (void)in_sizes; (void)n_in; (void)out_size;

  dim3 B256(256);
  k_init<<<1, 64, 0, stream>>>(flags);
  k_transposeB<<<dim3(10,10,4), B256, 0, stream>>>(aWq, WqT, 300, 300, 90000);
  k_transposeB<<<dim3(5,19,6), B256, 0, stream>>>(eWhh, WhhT, 600, 150, 90000);
  k_schema<<<128, B256, 0, stream>>>(temb, stok, eWih, eWhh, eb, SE);

  for (int i = 0; i < NTURNS; ++i) {
    const int kin  = (i+1 < MAXK) ? (i+1) : MAXK;
    const int kout = (i < MAXK) ? i : MAXK;
    const int nin = kin*128, nout = kout*64;
    const int NK = 64 + nin + nout;
    float* SEi = SE + (size_t)i*19200;
    float* SEo = SE + (size_t)(i+1)*19200;

    k_gemm_xe<<<dim3(5,8), B256, 0, stream>>>(utter, SEi, iseq + i*INLEN, 0,
                                              eWih + 360000, eb + 1200, Xg);
    k_rec<<<2, 640, 0, stream>>>(Xg, WhhT + 180000, ys1, fhs, fcs);
    k_gemm_xe<<<dim3(5,8), B256, 0, stream>>>(ys1, SEi, iseq + i*INLEN, 1,
                                              eWih + 720000, eb + 2400, Xg);
    k_rec<<<2, 640, 0, stream>>>(Xg, WhhT + 360000, ys2, fh, fc);
    k_schema_upd<<<64, B256, 0, stream>>>(SEi, ys2, SEo);
    if (i < MAXK)
      k_hist<<<60, B256, 0, stream>>>(fh, fc, ys2, HH, CH, XH, i);
    k_tables<<<3*NK + 63, B256, 0, stream>>>(SEo, XH, OH, aWk, dWih0, db0, tW, qemb,
                                             ogt + i*64, KW, G1K, G2K, EwB, nin, nout);
    k_transposeB<<<dim3(38, (NK+31)/32, 1), B256, 0, stream>>>(G1K, G1KT, NK, 1200, 0);
    k_dec<<<NWD, B256, 0, stream>>>(KW, G1KT, EwB, WqT, av, aWq, aWk,
                                    dWhh0, dWih1, dWhh1, db1, fh, fc, HH, CH,
                                    h0b, c0b, h1b, h2b, qWb, scb, Alog, H2lg,
                                    nin, nout, i, flags);
    k_ctxout2<<<63, B256, 0, stream>>>(H2lg, Alog, G2K, tW, colW, o63, t63, NK);
    k_score<<<dim3(118,4), B256, 0, stream>>>(o63, t63, sqlW, sqlb, SEo, dout + (size_t)i*63*VOUT);
    k_lsm<<<63, B256, 0, stream>>>(dout + (size_t)i*63*VOUT, amx);
    if (i < MAXK)
      k_amemb<<<1, B256, 0, stream>>>(amx, qemb, SEo, OH + (size_t)i*19200);
  }
}